// Round 16
// baseline (111.268 us; speedup 1.0000x reference)
//
#include <hip/hip_runtime.h>
#include <math.h>

typedef _Float16 f16x8 __attribute__((ext_vector_type(8)));   // MFMA A/B operand (4 VGPRs)
typedef _Float16 h2v   __attribute__((ext_vector_type(2)));
typedef float    f32x4 __attribute__((ext_vector_type(4)));   // MFMA C/D operand (16x16)
typedef __fp16   h2a   __attribute__((ext_vector_type(2)));   // cvt_pkrtz result
typedef unsigned u32x4 __attribute__((ext_vector_type(4)));

#define WS    10
#define HID   32
#define BDIM  256
#define NWAVE 4
#define GN    16                  // points per group = MFMA N (16x16 shape)
#define T_LEN 4096
#define NGRP  (T_LEN / GN)        // 256 groups per row; 64 per wave
#define PADN  4104                // padded f16 elements per LDS row copy

__device__ inline unsigned pack2u(float a, float b) {
    h2a t = __builtin_amdgcn_cvt_pkrtz(a, b);   // a -> low16, b -> high16
    return __builtin_bit_cast(unsigned, t);
}
__device__ inline unsigned relu2(unsigned u) {  // v_pk_max_f16 with 0
    h2v x = __builtin_bit_cast(h2v, u);
    h2v z = {(_Float16)0.0f, (_Float16)0.0f};
    return __builtin_bit_cast(unsigned, __builtin_elementwise_max(x, z));
}

// sigma: feature sitting in next-stage B-slot j (j = 8q+u). Lane (c,q)'s
// owned C/D rows across the two half-MFMAs {4q+r} u {16+4q+r} equal its
// needed B-slots {8q..8q+7} under this permutation -> C->B handoff is
// fully lane-local for the 16x16 shape (generalizes the r6 phi-trick).
__device__ inline int sigma(int j) {
    const int q = j >> 3, u = j & 7;
    return (u < 4) ? (4 * q + u) : (16 + 4 * q + (u - 4));
}

// 16x16x32 reformulation: 5 small MFMAs per 16-point group, 4-reg C/D.
// Total live state ~70 VGPRs -> accumulators stay in ARCH VGPRs: no
// v_accvgpr traffic, no MFMA(16-pass)->VALU hazard stalls (r9-r15: the
// 32x32 shape's 5x16-reg AGPR-resident accumulators were the invariant
// every flat round shared).
__global__ __launch_bounds__(BDIM, 4)
void hurst_mfma16(const float* __restrict__ returns,
                  const float* __restrict__ W1, const float* __restrict__ b1,
                  const float* __restrict__ W2, const float* __restrict__ b2,
                  const float* __restrict__ W3, const float* __restrict__ b3,
                  float* __restrict__ out)
{
    __shared__ __align__(16) _Float16 sbuf[2 * PADN];   // 16416 B

    const int tid  = threadIdx.x;
    const int wid  = tid >> 6;
    const int lane = tid & 63;
    const int c    = lane & 15;    // MFMA m (A-row) / n (B/C col)
    const int q    = lane >> 4;    // quad: k-octet (A/B) / row-quad (C/D)

    // ---- bias C-inits, C-layout row = 4q+r (half a: feat 4q+r; b: 16+4q+r) ----
    f32x4 b1va, b1vb, b2va, b2vb, b3v;
    #pragma unroll
    for (int r = 0; r < 4; ++r) {
        b1va[r] = b1[4 * q + r];
        b1vb[r] = b1[16 + 4 * q + r];
        b2va[r] = b2[4 * q + r];
        b2vb[r] = b2[16 + 4 * q + r];
        b3v[r]  = b3[0];
    }

    // ---- A-frags: A[m=lane&15][k=8q+jj]. W2/W3 k-rows permuted by sigma. ----
    f16x8 a1a, a1b, a2a, a2b, a3;
    #pragma unroll
    for (int jj = 0; jj < 8; ++jj) {
        const int k = 8 * q + jj;          // 0..31
        a1a[jj] = (k < WS) ? (_Float16)W1[k * HID + c]        : (_Float16)0.0f;
        a1b[jj] = (k < WS) ? (_Float16)W1[k * HID + 16 + c]   : (_Float16)0.0f;
        const int s = sigma(k);
        a2a[jj] = (_Float16)W2[s * HID + c];
        a2b[jj] = (_Float16)W2[s * HID + 16 + c];
        a3[jj]  = (_Float16)W3[s];         // broadcast over m
    }

    const float* rp   = returns + (size_t)blockIdx.x * T_LEN;
    float*       optr = out     + (size_t)blockIdx.x * T_LEN;

    // ---- build two packed-f16 row copies: buf0 pairs (e2j,e2j+1),
    //      buf1 pairs (e2j+1,e2j+2) — parity-shifted twin (verified r15) ----
    {
        float f[17];
        __builtin_memcpy(f, rp + 16 * tid, 64);
        const int nx = 16 * tid + 16;
        f[16] = rp[(nx < T_LEN) ? nx : (T_LEN - 1)];
        u32x4 q0a, q0b, q1a, q1b;
        #pragma unroll
        for (int k = 0; k < 4; ++k) {
            q0a[k] = pack2u(f[2 * k],     f[2 * k + 1]);
            q0b[k] = pack2u(f[8 + 2 * k], f[9 + 2 * k]);
            q1a[k] = pack2u(f[2 * k + 1], f[2 * k + 2]);
            q1b[k] = pack2u(f[9 + 2 * k], f[10 + 2 * k]);
        }
        unsigned* s32 = (unsigned*)sbuf;
        *(u32x4*)(s32 + 8 * tid)                  = q0a;
        *(u32x4*)(s32 + 8 * tid + 4)              = q0b;
        *(u32x4*)(s32 + (PADN / 2) + 8 * tid)     = q1a;
        *(u32x4*)(s32 + (PADN / 2) + 8 * tid + 4) = q1b;
    }
    __syncthreads();

    for (int g = wid; g < NGRP; g += NWAVE) {
        const int tg = g * GN + c;
        const int ws = (tg >= WS) ? (tg - WS) : 0;   // head points reuse window 0

        // ---- X B-frag: k=8q+jj window elems; q=0: e0..e7, q=1: e8,e9 + 0s,
        //      q>=2: all zero. One b128 LDS read; parity picks the copy. ----
        const unsigned eoff = (ws & 1) ? (unsigned)(PADN + ws - 1) : (unsigned)ws;
        u32x4 qv;
        __builtin_memcpy(&qv, (const char*)sbuf + 2 * (eoff + ((q == 1) ? 8u : 0u)), 16);
        u32x4 xu;
        xu[0] = (q < 2) ? qv[0] : 0u;
        xu[1] = (q == 0) ? qv[1] : 0u;
        xu[2] = (q == 0) ? qv[2] : 0u;
        xu[3] = (q == 0) ? qv[3] : 0u;
        const f16x8 xb = __builtin_bit_cast(f16x8, xu);

        // ---- L1: two independent half-MFMAs (features 0-15 / 16-31) ----
        const f32x4 d1a = __builtin_amdgcn_mfma_f32_16x16x32_f16(a1a, xb, b1va, 0, 0, 0);
        const f32x4 d1b = __builtin_amdgcn_mfma_f32_16x16x32_f16(a1b, xb, b1vb, 0, 0, 0);

        // relu+pack: [a0a1, a2a3, b0b1, b2b3] IS the L2 B-operand (sigma in A)
        u32x4 p1;
        p1[0] = relu2(pack2u(d1a[0], d1a[1]));
        p1[1] = relu2(pack2u(d1a[2], d1a[3]));
        p1[2] = relu2(pack2u(d1b[0], d1b[1]));
        p1[3] = relu2(pack2u(d1b[2], d1b[3]));
        const f16x8 h1 = __builtin_bit_cast(f16x8, p1);

        // ---- L2: K=32 in one MFMA per half ----
        const f32x4 d2a = __builtin_amdgcn_mfma_f32_16x16x32_f16(a2a, h1, b2va, 0, 0, 0);
        const f32x4 d2b = __builtin_amdgcn_mfma_f32_16x16x32_f16(a2b, h1, b2vb, 0, 0, 0);

        u32x4 p2;
        p2[0] = relu2(pack2u(d2a[0], d2a[1]));
        p2[1] = relu2(pack2u(d2a[2], d2a[3]));
        p2[2] = relu2(pack2u(d2b[0], d2b[1]));
        p2[3] = relu2(pack2u(d2b[2], d2b[3]));
        const f16x8 h2 = __builtin_bit_cast(f16x8, p2);

        // ---- L3: A = W3 broadcast over rows -> every D reg = out[c] + b3 ----
        const f32x4 d3 = __builtin_amdgcn_mfma_f32_16x16x32_f16(a3, h2, b3v, 0, 0, 0);

        // ---- sigmoid; quad 0 stores 16 consecutive floats (coalesced) ----
        const float o = 0.5f * __builtin_amdgcn_rcpf(1.0f + __expf(-d3[0]));
        if (q == 0)
            optr[tg] = o;
    }
}

extern "C" void kernel_launch(void* const* d_in, const int* in_sizes, int n_in,
                              void* d_out, int out_size, void* d_ws, size_t ws_size,
                              hipStream_t stream) {
    const float* returns = (const float*)d_in[0];
    const float* W1      = (const float*)d_in[1];
    const float* b1      = (const float*)d_in[2];
    const float* W2      = (const float*)d_in[3];
    const float* b2      = (const float*)d_in[4];
    const float* W3      = (const float*)d_in[5];
    const float* b3      = (const float*)d_in[6];
    float* out = (float*)d_out;

    const int B = out_size / T_LEN;   // 1024

    dim3 grid(B, 1, 1);               // one block per row; 4 blocks/CU, one round
    dim3 block(BDIM, 1, 1);
    hurst_mfma16<<<grid, block, 0, stream>>>(returns, W1, b1, W2, b2, W3, b3, out);
}